// Round 14
// baseline (149.309 us; speedup 1.0000x reference)
//
#include <hip/hip_runtime.h>
#include <hip/hip_bf16.h>
#include <math.h>

#define D_MODEL 1024
#define C_DIM   128
#define BATCH   4
#define SEQ     2048
#define BS_ROWS (BATCH*SEQ)

typedef float  f32x4 __attribute__((ext_vector_type(4)));
typedef short  s16x8 __attribute__((ext_vector_type(8)));
typedef unsigned short u16;
typedef unsigned short u16x4 __attribute__((ext_vector_type(4)));

__device__ inline u16 f2bf(float f){
    unsigned u = __builtin_bit_cast(unsigned, f);
    u += 0x7FFF + ((u >> 16) & 1);          // round-to-nearest-even
    return (u16)(u >> 16);
}

// async global->LDS, 16B per lane; LDS dest = wave-uniform base + lane*16
__device__ inline void gl_lds16(const u16* g, u16* l){
    __builtin_amdgcn_global_load_lds(
        (const __attribute__((address_space(1))) void*)g,
        (__attribute__((address_space(3))) void*)l,
        16, 0, 0);
}

template<int N> __device__ inline void wait_vm(){
    if constexpr (N <= 0)      asm volatile("s_waitcnt vmcnt(0)" ::: "memory");
    else if constexpr (N == 4) asm volatile("s_waitcnt vmcnt(4)" ::: "memory");
    else if constexpr (N == 6) asm volatile("s_waitcnt vmcnt(6)" ::: "memory");
    else if constexpr (N == 9) asm volatile("s_waitcnt vmcnt(9)" ::: "memory");
    else                       asm volatile("s_waitcnt vmcnt(0)" ::: "memory");
}

// ---------------------------------------------------------------------------
// gemm_8p: fine-phase pipelined GEMM for the two big GEMMs (m201-style).
// C[M,N] = A[M,K] @ BT[N,K]^T.  BM=256, BN=128, BK=64, 8 waves (4Mx2N,
// per-wave 64x64 = verified frag code). THREE static LDS K-tile buffers
// (144 KB): tile t read from buf t%3; tile t+2 staged into buf (t+2)%3 in
// half-tiles (h0 before vmcnt, h1 between MFMA clusters). Steady state
// vmcnt(9) retires exactly tile t's 6 loads, leaving t+1 (6) + t+2.h0 (3)
// in flight -> ~2 K-tiles (~1000cy) latency tolerance. Per tile: 16
// ds_read_b128 (both ks) after the opening barrier, then 2 setprio-wrapped
// 16-MFMA clusters, closing barrier. 2 barriers + 1 vmcnt per K-tile.
// CK: causal Keff=(mt%MTZ+1)*256; z = mt/MTZ (batch from m-tile).
// ---------------------------------------------------------------------------
template<int OUT_BF16, int CK, int RSCALE>
__launch_bounds__(512)
__global__ void gemm_8p(const u16* __restrict__ Ag, const u16* __restrict__ Bg,
                        void* __restrict__ Cg, const float* __restrict__ rowsum,
                        int gx, int gy, int MTZ,
                        int K, int lda, int ldb, int ldc,
                        long sA, long sBcol)
{
    constexpr int ASZ = 256 * 64, BSZ = 128 * 64;
    __shared__ u16 As0[ASZ]; __shared__ u16 As1[ASZ]; __shared__ u16 As2[ASZ];
    __shared__ u16 Bs0[BSZ]; __shared__ u16 Bs1[BSZ]; __shared__ u16 Bs2[BSZ];

    // XCD-chunked bijective swizzle (nwg % 8 == 0); mt fastest (share B-panel)
    const int nwg = gridDim.x;
    const int l   = (blockIdx.x & 7) * (nwg >> 3) + (blockIdx.x >> 3);
    const int mt  = l % gx;
    const int nt  = l / gx;                 // 0..gy-1
    (void)gy;
    const int z    = mt / MTZ;
    const int rowb = (mt % MTZ) * 256;      // A row base within batch
    const int mbase = mt * 256;             // C global row base
    const int nbase = nt * 128;
    const u16* Aa = Ag + (long)z * sA + (long)rowb * lda;
    const u16* Bb = Bg + (long)z * sBcol;
    const int tid = threadIdx.x, lane = tid & 63, wave = tid >> 6;
    const int wr = wave >> 1, wc = wave & 1;      // 4x2 wave grid
    int Keff = K;
    if (CK) { int ke = (mt % MTZ + 1) * 256; Keff = ke < K ? ke : K; }
    const int nkt = Keff >> 6;              // >= 4 (multiples of 4)

    f32x4 acc[4][4];
    #pragma unroll
    for (int m = 0; m < 4; ++m)
        #pragma unroll
        for (int n = 0; n < 4; ++n) acc[m][n] = (f32x4){0.f,0.f,0.f,0.f};

    const int sr  = lane >> 3;
    const int sc8 = (lane & 7) ^ sr;        // XOR-swizzled 16B col slot

    // hoisted staging pointers: A half h -> chunks h*16 + wave*2 + {0,1};
    // B half h -> chunk h*8 + wave. Advanced +64 elems per staged K-tile.
    const u16* aptrH[2][2];
    const u16* bptrH[2];
    #pragma unroll
    for (int h = 0; h < 2; ++h) {
        #pragma unroll
        for (int i = 0; i < 2; ++i) {
            const int c = h * 16 + wave * 2 + i;
            aptrH[h][i] = Aa + (size_t)(c * 8 + sr) * lda + sc8 * 8;
        }
        const int cb = h * 8 + wave;
        bptrH[h] = Bb + (size_t)(nbase + cb * 8 + sr) * ldb + sc8 * 8;
    }

    auto STAGE_HALF = [&](u16 (&Ad)[ASZ], u16 (&Bd)[BSZ], int h) {
        #pragma unroll
        for (int i = 0; i < 2; ++i) {
            const int c = h * 16 + wave * 2 + i;
            gl_lds16(aptrH[h][i], &Ad[c * 512]);
            aptrH[h][i] += 64;
        }
        const int cb = h * 8 + wave;
        gl_lds16(bptrH[h], &Bd[cb * 512]);
        bptrH[h] += 64;
    };

    auto TILE = [&](const u16 (&AR)[ASZ], const u16 (&BR)[BSZ],
                    u16 (&AW)[ASZ], u16 (&BW)[BSZ], int tt) {
        const bool st = (tt + 2 < nkt);
        if (st) STAGE_HALF(AW, BW, 0);
        // newer-than-tt halves in flight: t+1 (2 halves) + t+2.h0
        if (st)                   wait_vm<9>();
        else if (tt + 1 < nkt)    wait_vm<6>();
        else                      wait_vm<0>();
        __builtin_amdgcn_s_barrier();
        asm volatile("" ::: "memory");
        // load all frags for both k-slices (ks1 reads hide under ks0 MFMA)
        s16x8 af0[4], bf0[4], af1[4], bf1[4];
        const int k80 = (lane >> 4);
        const int k81 = 4 + (lane >> 4);
        #pragma unroll
        for (int m = 0; m < 4; ++m) {
            const int row = wr * 64 + m * 16 + (lane & 15);
            af0[m] = *(const s16x8*)&AR[row * 64 + ((k80 ^ (row & 7)) << 3)];
            af1[m] = *(const s16x8*)&AR[row * 64 + ((k81 ^ (row & 7)) << 3)];
        }
        #pragma unroll
        for (int n = 0; n < 4; ++n) {
            const int row = wc * 64 + n * 16 + (lane & 15);
            bf0[n] = *(const s16x8*)&BR[row * 64 + ((k80 ^ (row & 7)) << 3)];
            bf1[n] = *(const s16x8*)&BR[row * 64 + ((k81 ^ (row & 7)) << 3)];
        }
        __builtin_amdgcn_s_setprio(1);
        #pragma unroll
        for (int m = 0; m < 4; ++m)
            #pragma unroll
            for (int n = 0; n < 4; ++n)
                acc[m][n] = __builtin_amdgcn_mfma_f32_16x16x32_bf16(af0[m], bf0[n], acc[m][n], 0, 0, 0);
        __builtin_amdgcn_s_setprio(0);
        if (st) STAGE_HALF(AW, BW, 1);
        __builtin_amdgcn_s_setprio(1);
        #pragma unroll
        for (int m = 0; m < 4; ++m)
            #pragma unroll
            for (int n = 0; n < 4; ++n)
                acc[m][n] = __builtin_amdgcn_mfma_f32_16x16x32_bf16(af1[m], bf1[n], acc[m][n], 0, 0, 0);
        __builtin_amdgcn_s_setprio(0);
        __builtin_amdgcn_s_barrier();
        asm volatile("" ::: "memory");
    };

    // prologue: tiles 0 and 1 fully staged
    STAGE_HALF(As0, Bs0, 0); STAGE_HALF(As0, Bs0, 1);
    STAGE_HALF(As1, Bs1, 0); STAGE_HALF(As1, Bs1, 1);

    for (int t = 0; t < nkt; t += 3) {
        TILE(As0, Bs0, As2, Bs2, t);
        if (t + 1 >= nkt) break;
        TILE(As1, Bs1, As0, Bs0, t + 1);
        if (t + 2 >= nkt) break;
        TILE(As2, Bs2, As1, Bs1, t + 2);
    }

    // epilogue (verified C/D layout)
    const int lr = (lane >> 4) * 4, lc = lane & 15;
    #pragma unroll
    for (int m = 0; m < 4; ++m) {
        #pragma unroll
        for (int n = 0; n < 4; ++n) {
            const int gr = mbase + wr * 64 + m * 16 + lr;
            const int gc = nbase + wc * 64 + n * 16 + lc;
            #pragma unroll
            for (int r = 0; r < 4; ++r) {
                float f = acc[m][n][r];
                if (RSCALE) f /= rowsum[gr + r];
                const size_t off = (size_t)(gr + r) * ldc + gc;
                if (OUT_BF16) ((u16*)Cg)[off] = f2bf(f);
                else          ((float*)Cg)[off] = f;
            }
        }
    }
}

// ---------------------------------------------------------------------------
// gemm_bt (round-12, verified): qk projection + scores kernels.
// CSKIP now keeps the (even mt, nt==mt+1) boundary tile (causal-zeroed by
// EXPSUM) so the 256-row gemm_8p out-proj never reads unwritten sc.
// ---------------------------------------------------------------------------
template<int BM, int BN, int WM, int WN, int OUT_BF16, int MASK, int CSKIP,
         int CK, int QKF, int EXPSUM, int RSCALE, int ORD>
__launch_bounds__(WM*WN*64)
__global__ void gemm_bt(const u16* __restrict__ Ag, const u16* __restrict__ Bg,
                        const u16* __restrict__ Bg2,
                        void* __restrict__ Cg, void* __restrict__ Cg2,
                        const float* __restrict__ maskp,
                        float* __restrict__ rowsum,
                        int gx, int gy,
                        int K, int lda, int ldb, int ldc,
                        long sA, long sB, long sC, float scale)
{
    constexpr int W  = WM * WN;
    constexpr int PM = BM / WM, PN = BN / WN;
    constexpr int FM = PM / 16, FN = PN / 16;
    constexpr int CA = BM / 8 / W;
    constexpr int CB = BN / 8 / W;
    constexpr int NL = CA + CB;
    constexpr int ASZ = BM * 64, BSZ = BN * 64;
    __shared__ u16 As0[ASZ];
    __shared__ u16 As1[ASZ];
    __shared__ u16 Bs0[BSZ];
    __shared__ u16 Bs1[BSZ];

    const int nwg = gridDim.x;
    const int l   = (blockIdx.x & 7) * (nwg >> 3) + (blockIdx.x >> 3);
    int mt, nt, z, path = 0;
    if (ORD == 0) { mt = l % gx; const int r = l / gx; nt = r % gy; z = r / gy; }
    else          { nt = l % gy; const int r = l / gy; mt = r % gx; z = r / gx; }
    if (QKF) { constexpr int NT = C_DIM / BN; path = nt / NT; nt = nt % NT; }
    if (CSKIP && !(nt <= mt || (nt == mt + 1 && (mt & 1) == 0))) return;
    const u16* Aa = Ag + (long)z * sA;
    const u16* Bb = ((QKF && path) ? Bg2 : Bg) + (long)z * sB;
    const int tid = threadIdx.x, lane = tid & 63, wave = tid >> 6;
    const int wr = wave / WN, wc = wave % WN;
    const int mbase = mt * BM, nbase = nt * BN;
    int Keff = K;
    if (CK) { int ke = (mt + 1) * BM; Keff = ke < K ? ke : K; }
    const int nkt = Keff >> 6;

    f32x4 acc[FM][FN];
    #pragma unroll
    for (int m = 0; m < FM; ++m)
        #pragma unroll
        for (int n = 0; n < FN; ++n) acc[m][n] = (f32x4){0.f,0.f,0.f,0.f};

    const int sr  = lane >> 3;
    const int sc8 = (lane & 7) ^ sr;

    const u16* aptr[CA];
    const u16* bptr[CB];
    #pragma unroll
    for (int s = 0; s < CA; ++s)
        aptr[s] = Aa + (size_t)(mbase + (wave * CA + s) * 8 + sr) * lda + sc8 * 8;
    #pragma unroll
    for (int s = 0; s < CB; ++s)
        bptr[s] = Bb + (size_t)(nbase + (wave * CB + s) * 8 + sr) * ldb + sc8 * 8;

    auto STAGE = [&](u16 (&Ad)[ASZ], u16 (&Bd)[BSZ]) {
        #pragma unroll
        for (int s = 0; s < CA; ++s) { gl_lds16(aptr[s], &Ad[(wave * CA + s) * 512]); aptr[s] += 64; }
        #pragma unroll
        for (int s = 0; s < CB; ++s) { gl_lds16(bptr[s], &Bd[(wave * CB + s) * 512]); bptr[s] += 64; }
    };

    auto COMPUTE = [&](const u16 (&Ap)[ASZ], const u16 (&Bp)[BSZ]) {
        #pragma unroll
        for (int ks = 0; ks < 2; ++ks) {
            s16x8 af[FM], bfr[FN];
            const int k8 = ks * 4 + (lane >> 4);
            #pragma unroll
            for (int m = 0; m < FM; ++m) {
                const int row = wr * PM + m * 16 + (lane & 15);
                af[m] = *(const s16x8*)&Ap[row * 64 + ((k8 ^ (row & 7)) << 3)];
            }
            #pragma unroll
            for (int n = 0; n < FN; ++n) {
                const int row = wc * PN + n * 16 + (lane & 15);
                bfr[n] = *(const s16x8*)&Bp[row * 64 + ((k8 ^ (row & 7)) << 3)];
            }
            #pragma unroll
            for (int m = 0; m < FM; ++m)
                #pragma unroll
                for (int n = 0; n < FN; ++n)
                    acc[m][n] = __builtin_amdgcn_mfma_f32_16x16x32_bf16(af[m], bfr[n], acc[m][n], 0, 0, 0);
        }
    };

    STAGE(As0, Bs0);
    for (int t = 0; t < nkt; t += 2) {
        STAGE(As1, Bs1);
        wait_vm<NL>();
        __builtin_amdgcn_s_barrier();
        COMPUTE(As0, Bs0);
        __builtin_amdgcn_s_barrier();
        if (t + 2 < nkt) { STAGE(As0, Bs0); wait_vm<NL>(); }
        else             { wait_vm<0>(); }
        __builtin_amdgcn_s_barrier();
        COMPUTE(As1, Bs1);
        __builtin_amdgcn_s_barrier();
    }

    const bool kpath = QKF && path;
    void* Cout = kpath ? Cg2 : Cg;
    const int lr = (lane >> 4) * 4, lc = lane & 15;
    float rs[FM][4];
    if (EXPSUM) {
        #pragma unroll
        for (int m = 0; m < FM; ++m)
            #pragma unroll
            for (int r = 0; r < 4; ++r) rs[m][r] = 0.f;
    }
    #pragma unroll
    for (int m = 0; m < FM; ++m) {
        #pragma unroll
        for (int n = 0; n < FN; ++n) {
            const int gr = mbase + wr * PM + m * 16 + lr;
            const int gc = nbase + wc * PN + n * 16 + lc;
            #pragma unroll
            for (int r = 0; r < 4; ++r) {
                float f = acc[m][n][r] * scale;
                if (EXPSUM) {
                    f = (gc <= gr + r) ? __expf(f) : 0.f;
                    rs[m][r] += f;
                }
                if (RSCALE) f /= rowsum[(long)z * SEQ + gr + r];
                const size_t off = (size_t)(gr + r) * ldc + gc;
                if (MASK) { if (!kpath) f *= maskp[(long)z * sC + off]; }
                if (OUT_BF16) ((u16*)Cout + (long)z * sC)[off] = f2bf(f);
                else          ((float*)Cout + (long)z * sC)[off] = f;
            }
        }
    }
    if (EXPSUM) {
        #pragma unroll
        for (int m = 0; m < FM; ++m) {
            #pragma unroll
            for (int r = 0; r < 4; ++r) {
                float v = rs[m][r];
                v += __shfl_xor(v, 1); v += __shfl_xor(v, 2);
                v += __shfl_xor(v, 4); v += __shfl_xor(v, 8);
                if ((lane & 15) == 0) {
                    const int gr = mbase + wr * PM + m * 16 + lr + r;
                    atomicAdd(rowsum + (long)z * SEQ + gr, v);
                }
            }
        }
    }
}

// ---------------------------------------------------------------------------
__launch_bounds__(256)
__global__ void transpose_cvt(const float* __restrict__ in, u16* __restrict__ out,
                              int R, int Cc)
{
    __shared__ float t[32][33];
    const int c0 = blockIdx.x * 32, r0 = blockIdx.y * 32;
    const int tx = threadIdx.x & 31, ty = threadIdx.x >> 5;
    #pragma unroll
    for (int i = 0; i < 32; i += 8) t[ty + i][tx] = in[(size_t)(r0 + ty + i) * Cc + c0 + tx];
    __syncthreads();
    #pragma unroll
    for (int i = 0; i < 32; i += 8) out[(size_t)(c0 + ty + i) * R + r0 + tx] = f2bf(t[tx][ty + i]);
}

__launch_bounds__(256)
__global__ void convert_cvt(const float* __restrict__ in, u16* __restrict__ out, int n4)
{
    for (int i = blockIdx.x * 256 + threadIdx.x; i < n4; i += gridDim.x * 256) {
        float4 f = reinterpret_cast<const float4*>(in)[i];
        u16x4 o = { f2bf(f.x), f2bf(f.y), f2bf(f.z), f2bf(f.w) };
        reinterpret_cast<u16x4*>(out)[i] = o;
    }
}

// ---------------------------------------------------------------------------
extern "C" void kernel_launch(void* const* d_in, const int* in_sizes, int n_in,
                              void* d_out, int out_size, void* d_ws, size_t ws_size,
                              hipStream_t stream)
{
    const float* x    = (const float*)d_in[0];
    const float* A    = (const float*)d_in[1];
    const float* Bm   = (const float*)d_in[2];
    const float* ov   = (const float*)d_in[3];
    const float* mask = (const float*)d_in[4];

    // workspace layout: ~70.3 MiB
    char* w = (char*)d_ws;
    u16* xb   = (u16*)w; w += (size_t)BS_ROWS * D_MODEL * 2;   // x bf16 row-major
    u16* AbT  = (u16*)w; w += (size_t)C_DIM * D_MODEL * 2;     // A^T [C][D]
    u16* Bmb  = (u16*)w; w += (size_t)C_DIM * D_MODEL * 2;     // Bmat [C][D]
    u16* ovT  = (u16*)w; w += (size_t)D_MODEL * D_MODEL * 2;   // ov^T [e][d]
    u16* qm   = (u16*)w; w += (size_t)BS_ROWS * C_DIM * 2;     // masked q
    u16* kk   = (u16*)w; w += (size_t)BS_ROWS * C_DIM * 2;     // k
    u16* sc   = (u16*)w; w += (size_t)BATCH * SEQ * SEQ * 2;   // Pu = exp(scores)
    u16* xovT = (u16*)w; w += (size_t)D_MODEL * BS_ROWS * 2;   // (x@ov)^T [e][k]
    float* rowsum = (float*)w; w += (size_t)BS_ROWS * 4;       // softmax denoms

    hipMemsetAsync(rowsum, 0, (size_t)BS_ROWS * 4, stream);

    // prep
    convert_cvt<<<2048, 256, 0, stream>>>(x, xb, BS_ROWS * D_MODEL / 4);
    convert_cvt<<<128, 256, 0, stream>>>(Bm, Bmb, C_DIM * D_MODEL / 4);
    transpose_cvt<<<dim3(D_MODEL/32, D_MODEL/32, 1), 256, 0, stream>>>(ov, ovT, D_MODEL, D_MODEL);
    transpose_cvt<<<dim3(C_DIM/32, D_MODEL/32, 1), 256, 0, stream>>>(A, AbT, D_MODEL, C_DIM);

    // xovT[e][k] = ovT @ xb^T   (M=1024, N=8192, K=1024)
    // gemm_8p: 256x128, 8 waves, 4x64 = 256 blocks (1/CU), nkt=16
    gemm_8p<1,0,0><<<256, 512, 0, stream>>>(
        ovT, xb, xovT, nullptr,
        /*gx*/4, /*gy*/64, /*MTZ*/1 << 20,
        D_MODEL, D_MODEL, D_MODEL, BS_ROWS, 0, 0);

    // fused q & k projection: 64x64 tiles, 4 waves; 512 blocks (round-12)
    gemm_bt<64,64,2,2, 1,1,0,0,1,0,0, 1><<<512, 256, 0, stream>>>(
        xb, AbT, Bmb, qm, kk, mask, nullptr,
        /*gx*/128, /*gy*/4,
        D_MODEL, D_MODEL, D_MODEL, C_DIM, 0, 0, 0, 1.0f);

    // Pu = exp(qm @ kk^T / D) causal-zeroed (+ rowsum atomics); 1024 blocks
    // (keeps the even-mt boundary tile, written as zeros)
    gemm_bt<128,128,2,2, 1,0,1,0,0,1,0, 1><<<1024, 256, 0, stream>>>(
        qm, kk, nullptr, sc, nullptr, nullptr, rowsum,
        /*gx*/16, /*gy*/16,
        C_DIM, C_DIM, C_DIM, SEQ,
        (long)SEQ * C_DIM, (long)SEQ * C_DIM, (long)SEQ * SEQ, 1.0f / D_MODEL);

    // out = (Pu @ xovT^T) / rowsum   (causal, fp32 out)
    // gemm_8p: M=8192 global (batch from mt, MTZ=8), 32x8 = 256 blocks
    gemm_8p<0,1,1><<<256, 512, 0, stream>>>(
        sc, xovT, d_out, rowsum,
        /*gx*/32, /*gy*/8, /*MTZ*/8,
        SEQ, SEQ, BS_ROWS, D_MODEL,
        (long)SEQ * SEQ, (long)SEQ);
}

// Round 15
// 109.611 us; speedup vs baseline: 1.3622x; 1.3622x over previous
//
#include <hip/hip_runtime.h>
#include <hip/hip_bf16.h>
#include <math.h>

#define D_MODEL 1024
#define C_DIM   128
#define BATCH   4
#define SEQ     2048
#define BS_ROWS (BATCH*SEQ)

typedef float  f32x4 __attribute__((ext_vector_type(4)));
typedef short  s16x8 __attribute__((ext_vector_type(8)));
typedef unsigned short u16;
typedef unsigned short u16x4 __attribute__((ext_vector_type(4)));

__device__ inline u16 f2bf(float f){
    unsigned u = __builtin_bit_cast(unsigned, f);
    u += 0x7FFF + ((u >> 16) & 1);          // round-to-nearest-even
    return (u16)(u >> 16);
}

// async global->LDS, 16B per lane; LDS dest = wave-uniform base + lane*16
__device__ inline void gl_lds16(const u16* g, u16* l){
    __builtin_amdgcn_global_load_lds(
        (const __attribute__((address_space(1))) void*)g,
        (__attribute__((address_space(3))) void*)l,
        16, 0, 0);
}

// counted vmem wait: wait until <= N vmem instrs outstanding (this wave)
template<int N> __device__ inline void wait_vm(){
    if constexpr (N <= 0)      asm volatile("s_waitcnt vmcnt(0)" ::: "memory");
    else if constexpr (N == 4) asm volatile("s_waitcnt vmcnt(4)" ::: "memory");
    else if constexpr (N == 8) asm volatile("s_waitcnt vmcnt(8)" ::: "memory");
    else                       asm volatile("s_waitcnt vmcnt(0)" ::: "memory");
}

// ---------------------------------------------------------------------------
// bf16 MFMA GEMM (round-12 structure, best measured): static disjoint double
// buffers, 2x-unrolled K-loop, counted vmcnt(NL), raw barriers, hoisted
// staging pointers, XCD-chunked bijective blockIdx swizzle.
// Round-15 addition: PAIR flag for the causal out-proj — decode such that
// the presumed co-resident pair (l, l^32) gets complementary mt (work
// mt+1 vs 16-mt sums to 17 on every CU) and identical (nt,z) B-panel.
//   l bits (nwg=512, gx=16, gy=8, BATCH=4):
//     pairid = l&7; f=(l>>5)&1; mt = f ? 15-pairid : pairid;
//     ntz = ((l>>3)&3) | (((l>>6)&7)<<2); nt = ntz&7; z = ntz>>3.
// Flags: OUT_BF16; MASK (q-path mask); CSKIP (skip above-diagonal); CK
// (causal K-extent); QKF (fused q/k); EXPSUM (P=exp, causal-zero, rowsum
// atomics); RSCALE (divide by rowsum); ORD (panel-sharing order); PAIR.
// ---------------------------------------------------------------------------
template<int BM, int BN, int WM, int WN, int OUT_BF16, int MASK, int CSKIP,
         int CK, int QKF, int EXPSUM, int RSCALE, int ORD, int PAIR>
__launch_bounds__(WM*WN*64)
__global__ void gemm_bt(const u16* __restrict__ Ag, const u16* __restrict__ Bg,
                        const u16* __restrict__ Bg2,
                        void* __restrict__ Cg, void* __restrict__ Cg2,
                        const float* __restrict__ maskp,
                        float* __restrict__ rowsum,
                        int gx, int gy,
                        int K, int lda, int ldb, int ldc,
                        long sA, long sB, long sC, float scale)
{
    constexpr int W  = WM * WN;
    constexpr int PM = BM / WM, PN = BN / WN;
    constexpr int FM = PM / 16, FN = PN / 16;
    constexpr int CA = BM / 8 / W;          // A chunks (1KB) per wave per stage
    constexpr int CB = BN / 8 / W;
    constexpr int NL = CA + CB;             // gl_lds instrs per wave per stage
    constexpr int ASZ = BM * 64, BSZ = BN * 64;
    __shared__ u16 As0[ASZ];
    __shared__ u16 As1[ASZ];
    __shared__ u16 Bs0[BSZ];
    __shared__ u16 Bs1[BSZ];

    // XCD-chunked bijective swizzle (T1): nwg % 8 == 0 for all launches
    const int nwg = gridDim.x;
    const int l   = (blockIdx.x & 7) * (nwg >> 3) + (blockIdx.x >> 3);
    int mt, nt, z, path = 0;
    if (PAIR) {
        // complementary-mt pairing (nwg=512, gx=16, gy=8, BATCH=4)
        const int pairid = l & 7;
        const int f      = (l >> 5) & 1;
        mt = f ? (gx - 1 - pairid) : pairid;
        const int ntz = ((l >> 3) & 3) | (((l >> 6) & 7) << 2);
        nt = ntz & 7;
        z  = ntz >> 3;
    } else if (ORD == 0) {
        mt = l % gx; const int r = l / gx; nt = r % gy; z = r / gy;
    } else {
        nt = l % gy; const int r = l / gy; mt = r % gx; z = r / gx;
    }
    if (QKF) { constexpr int NT = C_DIM / BN; path = nt / NT; nt = nt % NT; }
    if (CSKIP && nt * BN >= (mt + 1) * BM) return;   // above causal diagonal
    const u16* Aa = Ag + (long)z * sA;
    const u16* Bb = ((QKF && path) ? Bg2 : Bg) + (long)z * sB;
    const int tid = threadIdx.x, lane = tid & 63, wave = tid >> 6;
    const int wr = wave / WN, wc = wave % WN;
    const int mbase = mt * BM, nbase = nt * BN;
    int Keff = K;
    if (CK) { int ke = (mt + 1) * BM; Keff = ke < K ? ke : K; }
    const int nkt = Keff >> 6;              // even by construction

    f32x4 acc[FM][FN];
    #pragma unroll
    for (int m = 0; m < FM; ++m)
        #pragma unroll
        for (int n = 0; n < FN; ++n) acc[m][n] = (f32x4){0.f,0.f,0.f,0.f};

    const int sr  = lane >> 3;                 // row within 8-row chunk
    const int sc8 = (lane & 7) ^ sr;           // XOR-swizzled 16B col slot

    // hoisted staging pointers: one per chunk, advanced 64 elts per STAGE
    const u16* aptr[CA];
    const u16* bptr[CB];
    #pragma unroll
    for (int s = 0; s < CA; ++s)
        aptr[s] = Aa + (size_t)(mbase + (wave * CA + s) * 8 + sr) * lda + sc8 * 8;
    #pragma unroll
    for (int s = 0; s < CB; ++s)
        bptr[s] = Bb + (size_t)(nbase + (wave * CB + s) * 8 + sr) * ldb + sc8 * 8;

    auto STAGE = [&](u16 (&Ad)[ASZ], u16 (&Bd)[BSZ]) {
        #pragma unroll
        for (int s = 0; s < CA; ++s) { gl_lds16(aptr[s], &Ad[(wave * CA + s) * 512]); aptr[s] += 64; }
        #pragma unroll
        for (int s = 0; s < CB; ++s) { gl_lds16(bptr[s], &Bd[(wave * CB + s) * 512]); bptr[s] += 64; }
    };

    auto COMPUTE = [&](const u16 (&Ap)[ASZ], const u16 (&Bp)[BSZ]) {
        #pragma unroll
        for (int ks = 0; ks < 2; ++ks) {
            s16x8 af[FM], bfr[FN];
            const int k8 = ks * 4 + (lane >> 4);
            #pragma unroll
            for (int m = 0; m < FM; ++m) {
                const int row = wr * PM + m * 16 + (lane & 15);
                af[m] = *(const s16x8*)&Ap[row * 64 + ((k8 ^ (row & 7)) << 3)];
            }
            #pragma unroll
            for (int n = 0; n < FN; ++n) {
                const int row = wc * PN + n * 16 + (lane & 15);
                bfr[n] = *(const s16x8*)&Bp[row * 64 + ((k8 ^ (row & 7)) << 3)];
            }
            #pragma unroll
            for (int m = 0; m < FM; ++m)
                #pragma unroll
                for (int n = 0; n < FN; ++n)
                    acc[m][n] = __builtin_amdgcn_mfma_f32_16x16x32_bf16(af[m], bfr[n], acc[m][n], 0, 0, 0);
        }
    };

    // prologue: tile 0 into buf0
    STAGE(As0, Bs0);
    for (int t = 0; t < nkt; t += 2) {
        // ---- phase A: compute tile t from buf0; prefetch t+1 into buf1 ----
        STAGE(As1, Bs1);                 // t+1 < nkt always (nkt even)
        wait_vm<NL>();                   // retire tile t's loads only
        __builtin_amdgcn_s_barrier();    // buf0 complete for all waves
        COMPUTE(As0, Bs0);
        __builtin_amdgcn_s_barrier();    // all waves done reading buf0
        // ---- phase B: compute tile t+1 from buf1; prefetch t+2 into buf0 ----
        if (t + 2 < nkt) { STAGE(As0, Bs0); wait_vm<NL>(); }
        else             { wait_vm<0>(); }
        __builtin_amdgcn_s_barrier();    // buf1 complete
        COMPUTE(As1, Bs1);
        __builtin_amdgcn_s_barrier();    // all waves done reading buf1
    }

    // epilogue: C/D layout col=lane&15, row=(lane>>4)*4+r (m89-verified)
    const bool kpath = QKF && path;
    void* Cout = kpath ? Cg2 : Cg;
    const int lr = (lane >> 4) * 4, lc = lane & 15;
    float rs[FM][4];
    if (EXPSUM) {
        #pragma unroll
        for (int m = 0; m < FM; ++m)
            #pragma unroll
            for (int r = 0; r < 4; ++r) rs[m][r] = 0.f;
    }
    #pragma unroll
    for (int m = 0; m < FM; ++m) {
        #pragma unroll
        for (int n = 0; n < FN; ++n) {
            const int gr = mbase + wr * PM + m * 16 + lr;
            const int gc = nbase + wc * PN + n * 16 + lc;
            #pragma unroll
            for (int r = 0; r < 4; ++r) {
                float f = acc[m][n][r] * scale;
                if (EXPSUM) {
                    f = (gc <= gr + r) ? __expf(f) : 0.f;   // causal + exp
                    rs[m][r] += f;
                }
                if (RSCALE) f /= rowsum[(long)z * SEQ + gr + r];
                const size_t off = (size_t)(gr + r) * ldc + gc;
                if (MASK) { if (!kpath) f *= maskp[(long)z * sC + off]; }
                if (OUT_BF16) ((u16*)Cout + (long)z * sC)[off] = f2bf(f);
                else          ((float*)Cout + (long)z * sC)[off] = f;
            }
        }
    }
    if (EXPSUM) {
        #pragma unroll
        for (int m = 0; m < FM; ++m) {
            #pragma unroll
            for (int r = 0; r < 4; ++r) {
                float v = rs[m][r];
                v += __shfl_xor(v, 1); v += __shfl_xor(v, 2);
                v += __shfl_xor(v, 4); v += __shfl_xor(v, 8);
                if ((lane & 15) == 0) {
                    const int gr = mbase + wr * PM + m * 16 + lr + r;
                    atomicAdd(rowsum + (long)z * SEQ + gr, v);
                }
            }
        }
    }
}

// ---------------------------------------------------------------------------
// fp32 -> bf16 transpose (32x32 LDS tiles): out[c][r] = in[r][c]
// ---------------------------------------------------------------------------
__launch_bounds__(256)
__global__ void transpose_cvt(const float* __restrict__ in, u16* __restrict__ out,
                              int R, int Cc)
{
    __shared__ float t[32][33];
    const int c0 = blockIdx.x * 32, r0 = blockIdx.y * 32;
    const int tx = threadIdx.x & 31, ty = threadIdx.x >> 5;
    #pragma unroll
    for (int i = 0; i < 32; i += 8) t[ty + i][tx] = in[(size_t)(r0 + ty + i) * Cc + c0 + tx];
    __syncthreads();
    #pragma unroll
    for (int i = 0; i < 32; i += 8) out[(size_t)(c0 + ty + i) * R + r0 + tx] = f2bf(t[tx][ty + i]);
}

// fp32 -> bf16 straight convert (vectorized), n4 = n/4
__launch_bounds__(256)
__global__ void convert_cvt(const float* __restrict__ in, u16* __restrict__ out, int n4)
{
    for (int i = blockIdx.x * 256 + threadIdx.x; i < n4; i += gridDim.x * 256) {
        float4 f = reinterpret_cast<const float4*>(in)[i];
        u16x4 o = { f2bf(f.x), f2bf(f.y), f2bf(f.z), f2bf(f.w) };
        reinterpret_cast<u16x4*>(out)[i] = o;
    }
}

// ---------------------------------------------------------------------------
extern "C" void kernel_launch(void* const* d_in, const int* in_sizes, int n_in,
                              void* d_out, int out_size, void* d_ws, size_t ws_size,
                              hipStream_t stream)
{
    const float* x    = (const float*)d_in[0];
    const float* A    = (const float*)d_in[1];
    const float* Bm   = (const float*)d_in[2];
    const float* ov   = (const float*)d_in[3];
    const float* mask = (const float*)d_in[4];

    // workspace layout: ~70.3 MiB
    char* w = (char*)d_ws;
    u16* xb   = (u16*)w; w += (size_t)BS_ROWS * D_MODEL * 2;   // x bf16 row-major
    u16* AbT  = (u16*)w; w += (size_t)C_DIM * D_MODEL * 2;     // A^T [C][D]
    u16* Bmb  = (u16*)w; w += (size_t)C_DIM * D_MODEL * 2;     // Bmat [C][D]
    u16* ovT  = (u16*)w; w += (size_t)D_MODEL * D_MODEL * 2;   // ov^T [e][d]
    u16* qm   = (u16*)w; w += (size_t)BS_ROWS * C_DIM * 2;     // masked q
    u16* kk   = (u16*)w; w += (size_t)BS_ROWS * C_DIM * 2;     // k
    u16* sc   = (u16*)w; w += (size_t)BATCH * SEQ * SEQ * 2;   // Pu = exp(scores)
    u16* xovT = (u16*)w; w += (size_t)D_MODEL * BS_ROWS * 2;   // (x@ov)^T [e][k]
    float* rowsum = (float*)w; w += (size_t)BS_ROWS * 4;       // softmax denoms

    hipMemsetAsync(rowsum, 0, (size_t)BS_ROWS * 4, stream);

    // prep: converts / transposes
    convert_cvt<<<2048, 256, 0, stream>>>(x, xb, BS_ROWS * D_MODEL / 4);
    convert_cvt<<<128, 256, 0, stream>>>(Bm, Bmb, C_DIM * D_MODEL / 4);
    transpose_cvt<<<dim3(D_MODEL/32, D_MODEL/32, 1), 256, 0, stream>>>(ov, ovT, D_MODEL, D_MODEL);
    transpose_cvt<<<dim3(C_DIM/32, D_MODEL/32, 1), 256, 0, stream>>>(A, AbT, D_MODEL, C_DIM);

    // xovT[e][k] = sum_d ovT[e][d] * xb[k][d]   (M=1024, N=8192, K=1024)
    // 128x128, 4 waves; 512 blocks; ORD=0 (8 consecutive share xb panel)
    gemm_bt<128,128,2,2, 1,0,0,0,0,0,0, 0,0><<<512, 256, 0, stream>>>(
        ovT, xb, nullptr, xovT, nullptr, nullptr, nullptr,
        /*gx*/8, /*gy*/64,
        D_MODEL, D_MODEL, D_MODEL, BS_ROWS, 0, 0, 0, 1.0f);

    // fused q & k projection: 64x64 tiles, 4 waves; 512 blocks; ORD=1
    gemm_bt<64,64,2,2, 1,1,0,0,1,0,0, 1,0><<<512, 256, 0, stream>>>(
        xb, AbT, Bmb, qm, kk, mask, nullptr,
        /*gx*/128, /*gy*/4,
        D_MODEL, D_MODEL, D_MODEL, C_DIM, 0, 0, 0, 1.0f);

    // Pu = exp(qm @ kk^T / D) causal-zeroed (+ rowsum atomics); 1024 blocks
    gemm_bt<128,128,2,2, 1,0,1,0,0,1,0, 1,0><<<1024, 256, 0, stream>>>(
        qm, kk, nullptr, sc, nullptr, nullptr, rowsum,
        /*gx*/16, /*gy*/16,
        C_DIM, C_DIM, C_DIM, SEQ,
        (long)SEQ * C_DIM, (long)SEQ * C_DIM, (long)SEQ * SEQ, 1.0f / D_MODEL);

    // out = (Pu @ xovT^T) / rowsum   (per batch, causal K-extent, fp32 out)
    // 128x128, 4 waves; 512 blocks; PAIR=1: co-resident (l, l^32) get
    // complementary mt -> uniform per-CU causal work, same (nt,z) B-panel
    gemm_bt<128,128,2,2, 0,0,0,1,0,0,1, 0,1><<<512, 256, 0, stream>>>(
        sc, xovT, nullptr, d_out, nullptr, nullptr, rowsum,
        /*gx*/16, /*gy*/8,
        SEQ, SEQ, BS_ROWS, D_MODEL,
        (long)SEQ * SEQ, (long)SEQ /*batch col offset in xovT*/, (long)SEQ * D_MODEL, 1.0f);
}

// Round 16
// 100.783 us; speedup vs baseline: 1.4815x; 1.0876x over previous
//
#include <hip/hip_runtime.h>
#include <hip/hip_bf16.h>
#include <math.h>

#define D_MODEL 1024
#define C_DIM   128
#define BATCH   4
#define SEQ     2048
#define BS_ROWS (BATCH*SEQ)

typedef float  f32x4 __attribute__((ext_vector_type(4)));
typedef short  s16x8 __attribute__((ext_vector_type(8)));
typedef unsigned short u16;
typedef unsigned short u16x4 __attribute__((ext_vector_type(4)));

__device__ inline u16 f2bf(float f){
    unsigned u = __builtin_bit_cast(unsigned, f);
    u += 0x7FFF + ((u >> 16) & 1);          // round-to-nearest-even
    return (u16)(u >> 16);
}

// async global->LDS, 16B per lane; LDS dest = wave-uniform base + lane*16
__device__ inline void gl_lds16(const u16* g, u16* l){
    __builtin_amdgcn_global_load_lds(
        (const __attribute__((address_space(1))) void*)g,
        (__attribute__((address_space(3))) void*)l,
        16, 0, 0);
}

// counted vmem wait: wait until <= N vmem instrs outstanding (this wave)
template<int N> __device__ inline void wait_vm(){
    if constexpr (N <= 0)      asm volatile("s_waitcnt vmcnt(0)" ::: "memory");
    else if constexpr (N == 4) asm volatile("s_waitcnt vmcnt(4)" ::: "memory");
    else if constexpr (N == 8) asm volatile("s_waitcnt vmcnt(8)" ::: "memory");
    else                       asm volatile("s_waitcnt vmcnt(0)" ::: "memory");
}

// ---------------------------------------------------------------------------
// bf16 MFMA GEMM (round-12 structure): static disjoint double buffers,
// 2x-unrolled K-loop, counted vmcnt(NL), raw barriers, hoisted staging
// pointers, XCD-chunked bijective blockIdx swizzle.
// PAIR=1 (out-proj, nwg=512, gx=16, gy=8): co-resident (l, l^32) get
//   complementary mt -> per-CU causal work sums to const; same (nt,z).
// PAIR=2 (scores, nwg=1024, gx=gy=16): f=(l>>5)&1, p=(l&31)|((l>>6)<<5),
//   z=p>>7, q=p&127, mt=f?15-(q&15):q&15, nt=f?15-(q>>4):q>>4.
//   Co-residents {l,l+32,l+64,l+96} = two complementary (mt,nt) pairs ->
//   exactly one of each pair is causally active -> uniform CU load.
// Flags: OUT_BF16; MASK; CSKIP; CK; QKF; EXPSUM; RSCALE; ORD; PAIR.
// ---------------------------------------------------------------------------
template<int BM, int BN, int WM, int WN, int OUT_BF16, int MASK, int CSKIP,
         int CK, int QKF, int EXPSUM, int RSCALE, int ORD, int PAIR>
__launch_bounds__(WM*WN*64)
__global__ void gemm_bt(const u16* __restrict__ Ag, const u16* __restrict__ Bg,
                        const u16* __restrict__ Bg2,
                        void* __restrict__ Cg, void* __restrict__ Cg2,
                        const float* __restrict__ maskp,
                        float* __restrict__ rowsum,
                        int gx, int gy,
                        int K, int lda, int ldb, int ldc,
                        long sA, long sB, long sC, float scale)
{
    constexpr int W  = WM * WN;
    constexpr int PM = BM / WM, PN = BN / WN;
    constexpr int FM = PM / 16, FN = PN / 16;
    constexpr int CA = BM / 8 / W;          // A chunks (1KB) per wave per stage
    constexpr int CB = BN / 8 / W;
    constexpr int NL = CA + CB;             // gl_lds instrs per wave per stage
    constexpr int ASZ = BM * 64, BSZ = BN * 64;
    __shared__ u16 As0[ASZ];
    __shared__ u16 As1[ASZ];
    __shared__ u16 Bs0[BSZ];
    __shared__ u16 Bs1[BSZ];

    // XCD-chunked bijective swizzle (T1): nwg % 8 == 0 for all launches
    const int nwg = gridDim.x;
    const int l   = (blockIdx.x & 7) * (nwg >> 3) + (blockIdx.x >> 3);
    int mt, nt, z, path = 0;
    if (PAIR == 1) {
        // complementary-mt pairing (nwg=512, gx=16, gy=8, BATCH=4)
        const int pairid = l & 7;
        const int f      = (l >> 5) & 1;
        mt = f ? (gx - 1 - pairid) : pairid;
        const int ntz = ((l >> 3) & 3) | (((l >> 6) & 7) << 2);
        nt = ntz & 7;
        z  = ntz >> 3;
    } else if (PAIR == 2) {
        // complementary-(mt,nt) pairing (nwg=1024, gx=gy=16, BATCH=4)
        const int f = (l >> 5) & 1;
        const int p = (l & 31) | ((l >> 6) << 5);   // 0..511
        z = p >> 7;
        const int q = p & 127;
        mt = f ? 15 - (q & 15) : (q & 15);
        nt = f ? 15 - (q >> 4) : (q >> 4);
    } else if (ORD == 0) {
        mt = l % gx; const int r = l / gx; nt = r % gy; z = r / gy;
    } else {
        nt = l % gy; const int r = l / gy; mt = r % gx; z = r / gx;
    }
    if (QKF) { constexpr int NT = C_DIM / BN; path = nt / NT; nt = nt % NT; }
    if (CSKIP && nt * BN >= (mt + 1) * BM) return;   // above causal diagonal
    const u16* Aa = Ag + (long)z * sA;
    const u16* Bb = ((QKF && path) ? Bg2 : Bg) + (long)z * sB;
    const int tid = threadIdx.x, lane = tid & 63, wave = tid >> 6;
    const int wr = wave / WN, wc = wave % WN;
    const int mbase = mt * BM, nbase = nt * BN;
    int Keff = K;
    if (CK) { int ke = (mt + 1) * BM; Keff = ke < K ? ke : K; }
    const int nkt = Keff >> 6;              // even by construction

    f32x4 acc[FM][FN];
    #pragma unroll
    for (int m = 0; m < FM; ++m)
        #pragma unroll
        for (int n = 0; n < FN; ++n) acc[m][n] = (f32x4){0.f,0.f,0.f,0.f};

    const int sr  = lane >> 3;                 // row within 8-row chunk
    const int sc8 = (lane & 7) ^ sr;           // XOR-swizzled 16B col slot

    // hoisted staging pointers: one per chunk, advanced 64 elts per STAGE
    const u16* aptr[CA];
    const u16* bptr[CB];
    #pragma unroll
    for (int s = 0; s < CA; ++s)
        aptr[s] = Aa + (size_t)(mbase + (wave * CA + s) * 8 + sr) * lda + sc8 * 8;
    #pragma unroll
    for (int s = 0; s < CB; ++s)
        bptr[s] = Bb + (size_t)(nbase + (wave * CB + s) * 8 + sr) * ldb + sc8 * 8;

    auto STAGE = [&](u16 (&Ad)[ASZ], u16 (&Bd)[BSZ]) {
        #pragma unroll
        for (int s = 0; s < CA; ++s) { gl_lds16(aptr[s], &Ad[(wave * CA + s) * 512]); aptr[s] += 64; }
        #pragma unroll
        for (int s = 0; s < CB; ++s) { gl_lds16(bptr[s], &Bd[(wave * CB + s) * 512]); bptr[s] += 64; }
    };

    auto COMPUTE = [&](const u16 (&Ap)[ASZ], const u16 (&Bp)[BSZ]) {
        #pragma unroll
        for (int ks = 0; ks < 2; ++ks) {
            s16x8 af[FM], bfr[FN];
            const int k8 = ks * 4 + (lane >> 4);
            #pragma unroll
            for (int m = 0; m < FM; ++m) {
                const int row = wr * PM + m * 16 + (lane & 15);
                af[m] = *(const s16x8*)&Ap[row * 64 + ((k8 ^ (row & 7)) << 3)];
            }
            #pragma unroll
            for (int n = 0; n < FN; ++n) {
                const int row = wc * PN + n * 16 + (lane & 15);
                bfr[n] = *(const s16x8*)&Bp[row * 64 + ((k8 ^ (row & 7)) << 3)];
            }
            #pragma unroll
            for (int m = 0; m < FM; ++m)
                #pragma unroll
                for (int n = 0; n < FN; ++n)
                    acc[m][n] = __builtin_amdgcn_mfma_f32_16x16x32_bf16(af[m], bfr[n], acc[m][n], 0, 0, 0);
        }
    };

    // prologue: tile 0 into buf0
    STAGE(As0, Bs0);
    for (int t = 0; t < nkt; t += 2) {
        // ---- phase A: compute tile t from buf0; prefetch t+1 into buf1 ----
        STAGE(As1, Bs1);                 // t+1 < nkt always (nkt even)
        wait_vm<NL>();                   // retire tile t's loads only
        __builtin_amdgcn_s_barrier();    // buf0 complete for all waves
        COMPUTE(As0, Bs0);
        __builtin_amdgcn_s_barrier();    // all waves done reading buf0
        // ---- phase B: compute tile t+1 from buf1; prefetch t+2 into buf0 ----
        if (t + 2 < nkt) { STAGE(As0, Bs0); wait_vm<NL>(); }
        else             { wait_vm<0>(); }
        __builtin_amdgcn_s_barrier();    // buf1 complete
        COMPUTE(As1, Bs1);
        __builtin_amdgcn_s_barrier();    // all waves done reading buf1
    }

    // epilogue: C/D layout col=lane&15, row=(lane>>4)*4+r (m89-verified)
    const bool kpath = QKF && path;
    void* Cout = kpath ? Cg2 : Cg;
    const int lr = (lane >> 4) * 4, lc = lane & 15;
    float rs[FM][4];
    if (EXPSUM) {
        #pragma unroll
        for (int m = 0; m < FM; ++m)
            #pragma unroll
            for (int r = 0; r < 4; ++r) rs[m][r] = 0.f;
    }
    #pragma unroll
    for (int m = 0; m < FM; ++m) {
        #pragma unroll
        for (int n = 0; n < FN; ++n) {
            const int gr = mbase + wr * PM + m * 16 + lr;
            const int gc = nbase + wc * PN + n * 16 + lc;
            #pragma unroll
            for (int r = 0; r < 4; ++r) {
                float f = acc[m][n][r] * scale;
                if (EXPSUM) {
                    f = (gc <= gr + r) ? __expf(f) : 0.f;   // causal + exp
                    rs[m][r] += f;
                }
                if (RSCALE) f /= rowsum[(long)z * SEQ + gr + r];
                const size_t off = (size_t)(gr + r) * ldc + gc;
                if (MASK) { if (!kpath) f *= maskp[(long)z * sC + off]; }
                if (OUT_BF16) ((u16*)Cout + (long)z * sC)[off] = f2bf(f);
                else          ((float*)Cout + (long)z * sC)[off] = f;
            }
        }
    }
    if (EXPSUM) {
        #pragma unroll
        for (int m = 0; m < FM; ++m) {
            #pragma unroll
            for (int r = 0; r < 4; ++r) {
                float v = rs[m][r];
                v += __shfl_xor(v, 1); v += __shfl_xor(v, 2);
                v += __shfl_xor(v, 4); v += __shfl_xor(v, 8);
                if ((lane & 15) == 0) {
                    const int gr = mbase + wr * PM + m * 16 + lr + r;
                    atomicAdd(rowsum + (long)z * SEQ + gr, v);
                }
            }
        }
    }
}

// ---------------------------------------------------------------------------
// fp32 -> bf16 transpose (32x32 LDS tiles): out[c][r] = in[r][c]
// ---------------------------------------------------------------------------
__launch_bounds__(256)
__global__ void transpose_cvt(const float* __restrict__ in, u16* __restrict__ out,
                              int R, int Cc)
{
    __shared__ float t[32][33];
    const int c0 = blockIdx.x * 32, r0 = blockIdx.y * 32;
    const int tx = threadIdx.x & 31, ty = threadIdx.x >> 5;
    #pragma unroll
    for (int i = 0; i < 32; i += 8) t[ty + i][tx] = in[(size_t)(r0 + ty + i) * Cc + c0 + tx];
    __syncthreads();
    #pragma unroll
    for (int i = 0; i < 32; i += 8) out[(size_t)(c0 + ty + i) * R + r0 + tx] = f2bf(t[tx][ty + i]);
}

// fp32 -> bf16 straight convert (vectorized), n4 = n/4.
// Also zero-fills rs[0..rsn) (rowsum) from the first rsn/256 blocks —
// replaces the 40us fillBuffer dispatch seen in the round-15 profile.
__launch_bounds__(256)
__global__ void convert_cvt(const float* __restrict__ in, u16* __restrict__ out,
                            int n4, float* __restrict__ rs, int rsn)
{
    const int gid = blockIdx.x * 256 + threadIdx.x;
    if (rs != nullptr && gid < rsn) rs[gid] = 0.f;
    for (int i = gid; i < n4; i += gridDim.x * 256) {
        float4 f = reinterpret_cast<const float4*>(in)[i];
        u16x4 o = { f2bf(f.x), f2bf(f.y), f2bf(f.z), f2bf(f.w) };
        reinterpret_cast<u16x4*>(out)[i] = o;
    }
}

// ---------------------------------------------------------------------------
extern "C" void kernel_launch(void* const* d_in, const int* in_sizes, int n_in,
                              void* d_out, int out_size, void* d_ws, size_t ws_size,
                              hipStream_t stream)
{
    const float* x    = (const float*)d_in[0];
    const float* A    = (const float*)d_in[1];
    const float* Bm   = (const float*)d_in[2];
    const float* ov   = (const float*)d_in[3];
    const float* mask = (const float*)d_in[4];

    // workspace layout: ~70.3 MiB
    char* w = (char*)d_ws;
    u16* xb   = (u16*)w; w += (size_t)BS_ROWS * D_MODEL * 2;   // x bf16 row-major
    u16* AbT  = (u16*)w; w += (size_t)C_DIM * D_MODEL * 2;     // A^T [C][D]
    u16* Bmb  = (u16*)w; w += (size_t)C_DIM * D_MODEL * 2;     // Bmat [C][D]
    u16* ovT  = (u16*)w; w += (size_t)D_MODEL * D_MODEL * 2;   // ov^T [e][d]
    u16* qm   = (u16*)w; w += (size_t)BS_ROWS * C_DIM * 2;     // masked q
    u16* kk   = (u16*)w; w += (size_t)BS_ROWS * C_DIM * 2;     // k
    u16* sc   = (u16*)w; w += (size_t)BATCH * SEQ * SEQ * 2;   // Pu = exp(scores)
    u16* xovT = (u16*)w; w += (size_t)D_MODEL * BS_ROWS * 2;   // (x@ov)^T [e][k]
    float* rowsum = (float*)w; w += (size_t)BS_ROWS * 4;       // softmax denoms

    // prep: converts / transposes (x-convert also zero-fills rowsum)
    convert_cvt<<<2048, 256, 0, stream>>>(x, xb, BS_ROWS * D_MODEL / 4, rowsum, BS_ROWS);
    convert_cvt<<<128, 256, 0, stream>>>(Bm, Bmb, C_DIM * D_MODEL / 4, nullptr, 0);
    transpose_cvt<<<dim3(D_MODEL/32, D_MODEL/32, 1), 256, 0, stream>>>(ov, ovT, D_MODEL, D_MODEL);
    transpose_cvt<<<dim3(C_DIM/32, D_MODEL/32, 1), 256, 0, stream>>>(A, AbT, D_MODEL, C_DIM);

    // xovT[e][k] = sum_d ovT[e][d] * xb[k][d]   (M=1024, N=8192, K=1024)
    // 128x128, 4 waves; 512 blocks; ORD=0 (8 consecutive share xb panel)
    gemm_bt<128,128,2,2, 1,0,0,0,0,0,0, 0,0><<<512, 256, 0, stream>>>(
        ovT, xb, nullptr, xovT, nullptr, nullptr, nullptr,
        /*gx*/8, /*gy*/64,
        D_MODEL, D_MODEL, D_MODEL, BS_ROWS, 0, 0, 0, 1.0f);

    // fused q & k projection: 64x64 tiles, 4 waves; 512 blocks; ORD=1
    gemm_bt<64,64,2,2, 1,1,0,0,1,0,0, 1,0><<<512, 256, 0, stream>>>(
        xb, AbT, Bmb, qm, kk, mask, nullptr,
        /*gx*/128, /*gy*/4,
        D_MODEL, D_MODEL, D_MODEL, C_DIM, 0, 0, 0, 1.0f);

    // Pu = exp(qm @ kk^T / D) causal-zeroed (+ rowsum atomics); 1024 blocks
    // PAIR=2: co-resident blocks get complementary (mt,nt) -> exactly one
    // causally active per pair -> uniform CU load
    gemm_bt<128,128,2,2, 1,0,1,0,0,1,0, 1,2><<<1024, 256, 0, stream>>>(
        qm, kk, nullptr, sc, nullptr, nullptr, rowsum,
        /*gx*/16, /*gy*/16,
        C_DIM, C_DIM, C_DIM, SEQ,
        (long)SEQ * C_DIM, (long)SEQ * C_DIM, (long)SEQ * SEQ, 1.0f / D_MODEL);

    // out = (Pu @ xovT^T) / rowsum   (per batch, causal K-extent, fp32 out)
    // 128x128, 4 waves; 512 blocks; PAIR=1: complementary-mt pairs
    gemm_bt<128,128,2,2, 0,0,0,1,0,0,1, 0,1><<<512, 256, 0, stream>>>(
        sc, xovT, nullptr, d_out, nullptr, nullptr, rowsum,
        /*gx*/16, /*gy*/8,
        SEQ, SEQ, BS_ROWS, D_MODEL,
        (long)SEQ * SEQ, (long)SEQ /*batch col offset in xovT*/, (long)SEQ * D_MODEL, 1.0f);
}

// Round 17
// 94.369 us; speedup vs baseline: 1.5822x; 1.0680x over previous
//
#include <hip/hip_runtime.h>
#include <hip/hip_bf16.h>
#include <math.h>

#define D_MODEL 1024
#define C_DIM   128
#define BATCH   4
#define SEQ     2048
#define BS_ROWS (BATCH*SEQ)

typedef float  f32x4 __attribute__((ext_vector_type(4)));
typedef short  s16x8 __attribute__((ext_vector_type(8)));
typedef unsigned short u16;
typedef unsigned short u16x4 __attribute__((ext_vector_type(4)));

__device__ inline u16 f2bf(float f){
    unsigned u = __builtin_bit_cast(unsigned, f);
    u += 0x7FFF + ((u >> 16) & 1);          // round-to-nearest-even
    return (u16)(u >> 16);
}

// async global->LDS, 16B per lane; LDS dest = wave-uniform base + lane*16
__device__ inline void gl_lds16(const u16* g, u16* l){
    __builtin_amdgcn_global_load_lds(
        (const __attribute__((address_space(1))) void*)g,
        (__attribute__((address_space(3))) void*)l,
        16, 0, 0);
}

// counted vmem wait: wait until <= N vmem instrs outstanding (this wave)
template<int N> __device__ inline void wait_vm(){
    if constexpr (N <= 0)      asm volatile("s_waitcnt vmcnt(0)" ::: "memory");
    else if constexpr (N == 4) asm volatile("s_waitcnt vmcnt(4)" ::: "memory");
    else if constexpr (N == 8) asm volatile("s_waitcnt vmcnt(8)" ::: "memory");
    else                       asm volatile("s_waitcnt vmcnt(0)" ::: "memory");
}

// ---------------------------------------------------------------------------
// gemm_core: the verified round-12/15 GEMM body (static disjoint double
// buffers, 2x-unrolled K-loop, counted vmcnt(NL), raw barriers, hoisted
// staging pointers). All batch offsets pre-applied by the caller.
// C[M,N] = scale * A[M,K] @ BT[N,K]^T for the (mt,nt) tile.
// Flags: OUT_BF16; MASK (f *= mp[off] when mp!=null); CK (causal K-extent);
// EXPSUM (P=exp, causal-zero, rowsum atomics); RSCALE (divide by rowsum).
// ---------------------------------------------------------------------------
template<int BM, int BN, int WM, int WN, int OUT_BF16, int MASK, int CK,
         int EXPSUM, int RSCALE>
__device__ __forceinline__ void gemm_core(
    u16 (&As0)[BM*64], u16 (&As1)[BM*64],
    u16 (&Bs0)[BN*64], u16 (&Bs1)[BN*64],
    const u16* __restrict__ Aa, const u16* __restrict__ Bb,
    void* __restrict__ Cout, const float* __restrict__ mp,
    float* __restrict__ rowsum,
    int mt, int nt, int K, int lda, int ldb, int ldc, float scale)
{
    constexpr int W  = WM * WN;
    constexpr int PM = BM / WM, PN = BN / WN;
    constexpr int FM = PM / 16, FN = PN / 16;
    constexpr int CA = BM / 8 / W;          // A chunks (1KB) per wave per stage
    constexpr int CB = BN / 8 / W;
    constexpr int NL = CA + CB;             // gl_lds instrs per wave per stage
    constexpr int ASZ = BM * 64, BSZ = BN * 64;

    const int tid = threadIdx.x, lane = tid & 63, wave = tid >> 6;
    const int wr = wave / WN, wc = wave % WN;
    const int mbase = mt * BM, nbase = nt * BN;
    int Keff = K;
    if (CK) { int ke = (mt + 1) * BM; Keff = ke < K ? ke : K; }
    const int nkt = Keff >> 6;              // even by construction

    f32x4 acc[FM][FN];
    #pragma unroll
    for (int m = 0; m < FM; ++m)
        #pragma unroll
        for (int n = 0; n < FN; ++n) acc[m][n] = (f32x4){0.f,0.f,0.f,0.f};

    const int sr  = lane >> 3;                 // row within 8-row chunk
    const int sc8 = (lane & 7) ^ sr;           // XOR-swizzled 16B col slot

    // hoisted staging pointers: one per chunk, advanced 64 elts per STAGE
    const u16* aptr[CA];
    const u16* bptr[CB];
    #pragma unroll
    for (int s = 0; s < CA; ++s)
        aptr[s] = Aa + (size_t)(mbase + (wave * CA + s) * 8 + sr) * lda + sc8 * 8;
    #pragma unroll
    for (int s = 0; s < CB; ++s)
        bptr[s] = Bb + (size_t)(nbase + (wave * CB + s) * 8 + sr) * ldb + sc8 * 8;

    auto STAGE = [&](u16 (&Ad)[ASZ], u16 (&Bd)[BSZ]) {
        #pragma unroll
        for (int s = 0; s < CA; ++s) { gl_lds16(aptr[s], &Ad[(wave * CA + s) * 512]); aptr[s] += 64; }
        #pragma unroll
        for (int s = 0; s < CB; ++s) { gl_lds16(bptr[s], &Bd[(wave * CB + s) * 512]); bptr[s] += 64; }
    };

    auto COMPUTE = [&](const u16 (&Ap)[ASZ], const u16 (&Bp)[BSZ]) {
        #pragma unroll
        for (int ks = 0; ks < 2; ++ks) {
            s16x8 af[FM], bfr[FN];
            const int k8 = ks * 4 + (lane >> 4);
            #pragma unroll
            for (int m = 0; m < FM; ++m) {
                const int row = wr * PM + m * 16 + (lane & 15);
                af[m] = *(const s16x8*)&Ap[row * 64 + ((k8 ^ (row & 7)) << 3)];
            }
            #pragma unroll
            for (int n = 0; n < FN; ++n) {
                const int row = wc * PN + n * 16 + (lane & 15);
                bfr[n] = *(const s16x8*)&Bp[row * 64 + ((k8 ^ (row & 7)) << 3)];
            }
            #pragma unroll
            for (int m = 0; m < FM; ++m)
                #pragma unroll
                for (int n = 0; n < FN; ++n)
                    acc[m][n] = __builtin_amdgcn_mfma_f32_16x16x32_bf16(af[m], bfr[n], acc[m][n], 0, 0, 0);
        }
    };

    // prologue: tile 0 into buf0
    STAGE(As0, Bs0);
    for (int t = 0; t < nkt; t += 2) {
        // ---- phase A: compute tile t from buf0; prefetch t+1 into buf1 ----
        STAGE(As1, Bs1);                 // t+1 < nkt always (nkt even)
        wait_vm<NL>();                   // retire tile t's loads only
        __builtin_amdgcn_s_barrier();    // buf0 complete for all waves
        COMPUTE(As0, Bs0);
        __builtin_amdgcn_s_barrier();    // all waves done reading buf0
        // ---- phase B: compute tile t+1 from buf1; prefetch t+2 into buf0 ----
        if (t + 2 < nkt) { STAGE(As0, Bs0); wait_vm<NL>(); }
        else             { wait_vm<0>(); }
        __builtin_amdgcn_s_barrier();    // buf1 complete
        COMPUTE(As1, Bs1);
        __builtin_amdgcn_s_barrier();    // all waves done reading buf1
    }

    // epilogue: C/D layout col=lane&15, row=(lane>>4)*4+r (m89-verified)
    const int lr = (lane >> 4) * 4, lc = lane & 15;
    float rs[FM][4];
    if (EXPSUM) {
        #pragma unroll
        for (int m = 0; m < FM; ++m)
            #pragma unroll
            for (int r = 0; r < 4; ++r) rs[m][r] = 0.f;
    }
    #pragma unroll
    for (int m = 0; m < FM; ++m) {
        #pragma unroll
        for (int n = 0; n < FN; ++n) {
            const int gr = mbase + wr * PM + m * 16 + lr;
            const int gc = nbase + wc * PN + n * 16 + lc;
            #pragma unroll
            for (int r = 0; r < 4; ++r) {
                float f = acc[m][n][r] * scale;
                if (EXPSUM) {
                    f = (gc <= gr + r) ? __expf(f) : 0.f;   // causal + exp
                    rs[m][r] += f;
                }
                if (RSCALE) f /= rowsum[gr + r];
                const size_t off = (size_t)(gr + r) * ldc + gc;
                if (MASK) { if (mp) f *= mp[off]; }
                if (OUT_BF16) ((u16*)Cout)[off] = f2bf(f);
                else          ((float*)Cout)[off] = f;
            }
        }
    }
    if (EXPSUM) {
        #pragma unroll
        for (int m = 0; m < FM; ++m) {
            #pragma unroll
            for (int r = 0; r < 4; ++r) {
                float v = rs[m][r];
                v += __shfl_xor(v, 1); v += __shfl_xor(v, 2);
                v += __shfl_xor(v, 4); v += __shfl_xor(v, 8);
                if ((lane & 15) == 0) {
                    const int gr = mbase + wr * PM + m * 16 + lr + r;
                    atomicAdd(rowsum + gr, v);
                }
            }
        }
    }
}

// ---------------------------------------------------------------------------
// gemm_bt wrapper: decode (XCD swizzle / ORD / PAIR / QKF / CSKIP), then core.
// PAIR=1 (out-proj, nwg=512, gx=16, gy=8): co-resident (l, l^32) get
//   complementary mt -> per-CU causal work sums to const; same (nt,z).
// ---------------------------------------------------------------------------
template<int BM, int BN, int WM, int WN, int OUT_BF16, int MASK, int CSKIP,
         int CK, int QKF, int EXPSUM, int RSCALE, int ORD, int PAIR>
__launch_bounds__(WM*WN*64)
__global__ void gemm_bt(const u16* __restrict__ Ag, const u16* __restrict__ Bg,
                        const u16* __restrict__ Bg2,
                        void* __restrict__ Cg, void* __restrict__ Cg2,
                        const float* __restrict__ maskp,
                        float* __restrict__ rowsum,
                        int gx, int gy,
                        int K, int lda, int ldb, int ldc,
                        long sA, long sB, long sC, float scale)
{
    constexpr int ASZ = BM * 64, BSZ = BN * 64;
    __shared__ u16 As0[ASZ];
    __shared__ u16 As1[ASZ];
    __shared__ u16 Bs0[BSZ];
    __shared__ u16 Bs1[BSZ];

    // XCD-chunked bijective swizzle (T1): nwg % 8 == 0 for all launches
    const int nwg = gridDim.x;
    const int l   = (blockIdx.x & 7) * (nwg >> 3) + (blockIdx.x >> 3);
    int mt, nt, z, path = 0;
    if (PAIR == 1) {
        const int pairid = l & 7;
        const int f      = (l >> 5) & 1;
        mt = f ? (gx - 1 - pairid) : pairid;
        const int ntz = ((l >> 3) & 3) | (((l >> 6) & 7) << 2);
        nt = ntz & 7;
        z  = ntz >> 3;
    } else if (ORD == 0) {
        mt = l % gx; const int r = l / gx; nt = r % gy; z = r / gy;
    } else {
        nt = l % gy; const int r = l / gy; mt = r % gx; z = r / gx;
    }
    if (QKF) { constexpr int NT = C_DIM / BN; path = nt / NT; nt = nt % NT; }
    if (CSKIP && nt * BN >= (mt + 1) * BM) return;   // above causal diagonal

    const bool kpath = QKF && path;
    const u16* Aa = Ag + (long)z * sA;
    const u16* Bb = (kpath ? Bg2 : Bg) + (long)z * sB;
    void* CoutBase = kpath ? Cg2 : Cg;
    void* Cout = OUT_BF16 ? (void*)((u16*)CoutBase + (long)z * sC)
                          : (void*)((float*)CoutBase + (long)z * sC);
    const float* mp = (MASK && !kpath && maskp) ? maskp + (long)z * sC : nullptr;
    float* rsz = rowsum ? rowsum + (long)z * SEQ : nullptr;

    gemm_core<BM,BN,WM,WN,OUT_BF16,MASK,CK,EXPSUM,RSCALE>(
        As0, As1, Bs0, Bs1, Aa, Bb, Cout, mp, rsz,
        mt, nt, K, lda, ldb, ldc, scale);
}

// ---------------------------------------------------------------------------
// Fused scores + xovT dispatch: both paths are latency-bound 128x128/4-wave
// GEMMs; merging them doubles independent blocks/CU so one block's staging
// stalls hide under the other's MFMA. Scores occupy bids [0,1024) with the
// round-16 PAIR=2 decode (unchanged); xovT occupies [1024,1536) with its
// ORD=0 decode. Scores' ~50% dead blocks exit instantly, pulling xovT
// blocks in early -> tail overlap.
// ---------------------------------------------------------------------------
__launch_bounds__(256)
__global__ void scores_xov_fused(const u16* __restrict__ qm,
                                 const u16* __restrict__ kk,
                                 u16* __restrict__ sc,
                                 float* __restrict__ rowsum,
                                 const u16* __restrict__ ovT,
                                 const u16* __restrict__ xb,
                                 u16* __restrict__ xovT)
{
    __shared__ u16 As0[128*64];
    __shared__ u16 As1[128*64];
    __shared__ u16 Bs0[128*64];
    __shared__ u16 Bs1[128*64];

    const int bid = blockIdx.x;
    if (bid < 1024) {
        // scores: Pu = exp(qm @ kk^T / D), causal-zeroed, rowsum atomics
        // PAIR=2 decode (nwg=1024, gx=gy=16, BATCH=4) — round-16 verified
        const int l = (bid & 7) * 128 + (bid >> 3);
        const int f = (l >> 5) & 1;
        const int p = (l & 31) | ((l >> 6) << 5);   // 0..511
        const int z = p >> 7;
        const int q = p & 127;
        const int mt = f ? 15 - (q & 15) : (q & 15);
        const int nt = f ? 15 - (q >> 4) : (q >> 4);
        if (nt > mt) return;                         // above causal diagonal
        gemm_core<128,128,2,2, 1,0,0,1,0>(
            As0, As1, Bs0, Bs1,
            qm + (long)z * SEQ * C_DIM,
            kk + (long)z * SEQ * C_DIM,
            sc + (long)z * SEQ * SEQ,
            nullptr,
            rowsum + (long)z * SEQ,
            mt, nt, C_DIM, C_DIM, C_DIM, SEQ, 1.0f / D_MODEL);
    } else {
        // xovT[e][k] = sum_d ovT[e][d] * xb[k][d]  (M=1024, N=8192, K=1024)
        // ORD=0 decode over local grid (nwg=512, gx=8, gy=64, z=0)
        const int local = bid - 1024;
        const int l = (local & 7) * 64 + (local >> 3);
        const int mt = l % 8;
        const int nt = l / 8;                        // 0..63
        gemm_core<128,128,2,2, 1,0,0,0,0>(
            As0, As1, Bs0, Bs1,
            ovT, xb, xovT, nullptr, nullptr,
            mt, nt, D_MODEL, D_MODEL, D_MODEL, BS_ROWS, 1.0f);
    }
}

// ---------------------------------------------------------------------------
// fp32 -> bf16 transpose (32x32 LDS tiles): out[c][r] = in[r][c]
// ---------------------------------------------------------------------------
__launch_bounds__(256)
__global__ void transpose_cvt(const float* __restrict__ in, u16* __restrict__ out,
                              int R, int Cc)
{
    __shared__ float t[32][33];
    const int c0 = blockIdx.x * 32, r0 = blockIdx.y * 32;
    const int tx = threadIdx.x & 31, ty = threadIdx.x >> 5;
    #pragma unroll
    for (int i = 0; i < 32; i += 8) t[ty + i][tx] = in[(size_t)(r0 + ty + i) * Cc + c0 + tx];
    __syncthreads();
    #pragma unroll
    for (int i = 0; i < 32; i += 8) out[(size_t)(c0 + ty + i) * R + r0 + tx] = f2bf(t[tx][ty + i]);
}

// fp32 -> bf16 straight convert (vectorized), n4 = n/4.
// Also zero-fills rs[0..rsn) (rowsum) from the first rsn/256 blocks.
__launch_bounds__(256)
__global__ void convert_cvt(const float* __restrict__ in, u16* __restrict__ out,
                            int n4, float* __restrict__ rs, int rsn)
{
    const int gid = blockIdx.x * 256 + threadIdx.x;
    if (rs != nullptr && gid < rsn) rs[gid] = 0.f;
    for (int i = gid; i < n4; i += gridDim.x * 256) {
        float4 f = reinterpret_cast<const float4*>(in)[i];
        u16x4 o = { f2bf(f.x), f2bf(f.y), f2bf(f.z), f2bf(f.w) };
        reinterpret_cast<u16x4*>(out)[i] = o;
    }
}

// ---------------------------------------------------------------------------
extern "C" void kernel_launch(void* const* d_in, const int* in_sizes, int n_in,
                              void* d_out, int out_size, void* d_ws, size_t ws_size,
                              hipStream_t stream)
{
    const float* x    = (const float*)d_in[0];
    const float* A    = (const float*)d_in[1];
    const float* Bm   = (const float*)d_in[2];
    const float* ov   = (const float*)d_in[3];
    const float* mask = (const float*)d_in[4];

    // workspace layout: ~70.3 MiB
    char* w = (char*)d_ws;
    u16* xb   = (u16*)w; w += (size_t)BS_ROWS * D_MODEL * 2;   // x bf16 row-major
    u16* AbT  = (u16*)w; w += (size_t)C_DIM * D_MODEL * 2;     // A^T [C][D]
    u16* Bmb  = (u16*)w; w += (size_t)C_DIM * D_MODEL * 2;     // Bmat [C][D]
    u16* ovT  = (u16*)w; w += (size_t)D_MODEL * D_MODEL * 2;   // ov^T [e][d]
    u16* qm   = (u16*)w; w += (size_t)BS_ROWS * C_DIM * 2;     // masked q
    u16* kk   = (u16*)w; w += (size_t)BS_ROWS * C_DIM * 2;     // k
    u16* sc   = (u16*)w; w += (size_t)BATCH * SEQ * SEQ * 2;   // Pu = exp(scores)
    u16* xovT = (u16*)w; w += (size_t)D_MODEL * BS_ROWS * 2;   // (x@ov)^T [e][k]
    float* rowsum = (float*)w; w += (size_t)BS_ROWS * 4;       // softmax denoms

    // prep: converts / transposes (x-convert also zero-fills rowsum)
    convert_cvt<<<2048, 256, 0, stream>>>(x, xb, BS_ROWS * D_MODEL / 4, rowsum, BS_ROWS);
    convert_cvt<<<128, 256, 0, stream>>>(Bm, Bmb, C_DIM * D_MODEL / 4, nullptr, 0);
    transpose_cvt<<<dim3(D_MODEL/32, D_MODEL/32, 1), 256, 0, stream>>>(ov, ovT, D_MODEL, D_MODEL);
    transpose_cvt<<<dim3(C_DIM/32, D_MODEL/32, 1), 256, 0, stream>>>(A, AbT, D_MODEL, C_DIM);

    // fused q & k projection: 64x64 tiles, 4 waves; 512 blocks; ORD=1
    gemm_bt<64,64,2,2, 1,1,0,0,1,0,0, 1,0><<<512, 256, 0, stream>>>(
        xb, AbT, Bmb, qm, kk, mask, nullptr,
        /*gx*/128, /*gy*/4,
        D_MODEL, D_MODEL, D_MODEL, C_DIM, 0, 0, 0, 1.0f);

    // fused dispatch: scores (PAIR=2, 1024 bids) + xovT (512 bids)
    scores_xov_fused<<<1536, 256, 0, stream>>>(qm, kk, sc, rowsum, ovT, xb, xovT);

    // out = (Pu @ xovT^T) / rowsum   (per batch, causal K-extent, fp32 out)
    // 128x128, 4 waves; 512 blocks; PAIR=1: complementary-mt pairs
    gemm_bt<128,128,2,2, 0,0,0,1,0,0,1, 0,1><<<512, 256, 0, stream>>>(
        sc, xovT, nullptr, d_out, nullptr, nullptr, rowsum,
        /*gx*/16, /*gy*/8,
        SEQ, SEQ, BS_ROWS, D_MODEL,
        (long)SEQ * SEQ, (long)SEQ /*batch col offset in xovT*/, (long)SEQ * D_MODEL, 1.0f);
}

// Round 18
// 88.367 us; speedup vs baseline: 1.6896x; 1.0679x over previous
//
#include <hip/hip_runtime.h>
#include <hip/hip_bf16.h>
#include <math.h>

#define D_MODEL 1024
#define C_DIM   128
#define BATCH   4
#define SEQ     2048
#define BS_ROWS (BATCH*SEQ)

typedef float  f32x4 __attribute__((ext_vector_type(4)));
typedef short  s16x8 __attribute__((ext_vector_type(8)));
typedef unsigned short u16;
typedef unsigned short u16x4 __attribute__((ext_vector_type(4)));

__device__ inline u16 f2bf(float f){
    unsigned u = __builtin_bit_cast(unsigned, f);
    u += 0x7FFF + ((u >> 16) & 1);          // round-to-nearest-even
    return (u16)(u >> 16);
}

// async global->LDS, 16B per lane; LDS dest = wave-uniform base + lane*16
__device__ inline void gl_lds16(const u16* g, u16* l){
    __builtin_amdgcn_global_load_lds(
        (const __attribute__((address_space(1))) void*)g,
        (__attribute__((address_space(3))) void*)l,
        16, 0, 0);
}

// counted vmem wait: wait until <= N vmem instrs outstanding (this wave)
template<int N> __device__ inline void wait_vm(){
    if constexpr (N <= 0)      asm volatile("s_waitcnt vmcnt(0)" ::: "memory");
    else if constexpr (N == 4) asm volatile("s_waitcnt vmcnt(4)" ::: "memory");
    else if constexpr (N == 8) asm volatile("s_waitcnt vmcnt(8)" ::: "memory");
    else                       asm volatile("s_waitcnt vmcnt(0)" ::: "memory");
}

// ---------------------------------------------------------------------------
// gemm_core: the verified round-12/15 GEMM body (static disjoint double
// buffers, 2x-unrolled K-loop, counted vmcnt(NL), raw barriers, hoisted
// staging pointers). All batch offsets pre-applied by the caller.
// C[M,N] = scale * A[M,K] @ BT[N,K]^T for the (mt,nt) tile.
// Flags: OUT_BF16; MASK (f *= mp[off] when mp!=null); CK (causal K-extent);
// EXPSUM (P=exp, causal-zero, rowsum atomics); RSCALE (divide by rowsum).
// ---------------------------------------------------------------------------
template<int BM, int BN, int WM, int WN, int OUT_BF16, int MASK, int CK,
         int EXPSUM, int RSCALE>
__device__ __forceinline__ void gemm_core(
    u16 (&As0)[BM*64], u16 (&As1)[BM*64],
    u16 (&Bs0)[BN*64], u16 (&Bs1)[BN*64],
    const u16* __restrict__ Aa, const u16* __restrict__ Bb,
    void* __restrict__ Cout, const float* __restrict__ mp,
    float* __restrict__ rowsum,
    int mt, int nt, int K, int lda, int ldb, int ldc, float scale)
{
    constexpr int W  = WM * WN;
    constexpr int PM = BM / WM, PN = BN / WN;
    constexpr int FM = PM / 16, FN = PN / 16;
    constexpr int CA = BM / 8 / W;          // A chunks (1KB) per wave per stage
    constexpr int CB = BN / 8 / W;
    constexpr int NL = CA + CB;             // gl_lds instrs per wave per stage
    constexpr int ASZ = BM * 64, BSZ = BN * 64;

    const int tid = threadIdx.x, lane = tid & 63, wave = tid >> 6;
    const int wr = wave / WN, wc = wave % WN;
    const int mbase = mt * BM, nbase = nt * BN;
    int Keff = K;
    if (CK) { int ke = (mt + 1) * BM; Keff = ke < K ? ke : K; }
    const int nkt = Keff >> 6;              // even by construction

    f32x4 acc[FM][FN];
    #pragma unroll
    for (int m = 0; m < FM; ++m)
        #pragma unroll
        for (int n = 0; n < FN; ++n) acc[m][n] = (f32x4){0.f,0.f,0.f,0.f};

    const int sr  = lane >> 3;                 // row within 8-row chunk
    const int sc8 = (lane & 7) ^ sr;           // XOR-swizzled 16B col slot

    // hoisted staging pointers: one per chunk, advanced 64 elts per STAGE
    const u16* aptr[CA];
    const u16* bptr[CB];
    #pragma unroll
    for (int s = 0; s < CA; ++s)
        aptr[s] = Aa + (size_t)(mbase + (wave * CA + s) * 8 + sr) * lda + sc8 * 8;
    #pragma unroll
    for (int s = 0; s < CB; ++s)
        bptr[s] = Bb + (size_t)(nbase + (wave * CB + s) * 8 + sr) * ldb + sc8 * 8;

    auto STAGE = [&](u16 (&Ad)[ASZ], u16 (&Bd)[BSZ]) {
        #pragma unroll
        for (int s = 0; s < CA; ++s) { gl_lds16(aptr[s], &Ad[(wave * CA + s) * 512]); aptr[s] += 64; }
        #pragma unroll
        for (int s = 0; s < CB; ++s) { gl_lds16(bptr[s], &Bd[(wave * CB + s) * 512]); bptr[s] += 64; }
    };

    auto COMPUTE = [&](const u16 (&Ap)[ASZ], const u16 (&Bp)[BSZ]) {
        #pragma unroll
        for (int ks = 0; ks < 2; ++ks) {
            s16x8 af[FM], bfr[FN];
            const int k8 = ks * 4 + (lane >> 4);
            #pragma unroll
            for (int m = 0; m < FM; ++m) {
                const int row = wr * PM + m * 16 + (lane & 15);
                af[m] = *(const s16x8*)&Ap[row * 64 + ((k8 ^ (row & 7)) << 3)];
            }
            #pragma unroll
            for (int n = 0; n < FN; ++n) {
                const int row = wc * PN + n * 16 + (lane & 15);
                bfr[n] = *(const s16x8*)&Bp[row * 64 + ((k8 ^ (row & 7)) << 3)];
            }
            #pragma unroll
            for (int m = 0; m < FM; ++m)
                #pragma unroll
                for (int n = 0; n < FN; ++n)
                    acc[m][n] = __builtin_amdgcn_mfma_f32_16x16x32_bf16(af[m], bfr[n], acc[m][n], 0, 0, 0);
        }
    };

    // prologue: tile 0 into buf0
    STAGE(As0, Bs0);
    for (int t = 0; t < nkt; t += 2) {
        // ---- phase A: compute tile t from buf0; prefetch t+1 into buf1 ----
        STAGE(As1, Bs1);                 // t+1 < nkt always (nkt even)
        wait_vm<NL>();                   // retire tile t's loads only
        __builtin_amdgcn_s_barrier();    // buf0 complete for all waves
        COMPUTE(As0, Bs0);
        __builtin_amdgcn_s_barrier();    // all waves done reading buf0
        // ---- phase B: compute tile t+1 from buf1; prefetch t+2 into buf0 ----
        if (t + 2 < nkt) { STAGE(As0, Bs0); wait_vm<NL>(); }
        else             { wait_vm<0>(); }
        __builtin_amdgcn_s_barrier();    // buf1 complete
        COMPUTE(As1, Bs1);
        __builtin_amdgcn_s_barrier();    // all waves done reading buf1
    }

    // epilogue: C/D layout col=lane&15, row=(lane>>4)*4+r (m89-verified)
    const int lr = (lane >> 4) * 4, lc = lane & 15;
    float rs[FM][4];
    if (EXPSUM) {
        #pragma unroll
        for (int m = 0; m < FM; ++m)
            #pragma unroll
            for (int r = 0; r < 4; ++r) rs[m][r] = 0.f;
    }
    #pragma unroll
    for (int m = 0; m < FM; ++m) {
        #pragma unroll
        for (int n = 0; n < FN; ++n) {
            const int gr = mbase + wr * PM + m * 16 + lr;
            const int gc = nbase + wc * PN + n * 16 + lc;
            #pragma unroll
            for (int r = 0; r < 4; ++r) {
                float f = acc[m][n][r] * scale;
                if (EXPSUM) {
                    f = (gc <= gr + r) ? __expf(f) : 0.f;   // causal + exp
                    rs[m][r] += f;
                }
                if (RSCALE) f /= rowsum[gr + r];
                const size_t off = (size_t)(gr + r) * ldc + gc;
                if (MASK) { if (mp) f *= mp[off]; }
                if (OUT_BF16) ((u16*)Cout)[off] = f2bf(f);
                else          ((float*)Cout)[off] = f;
            }
        }
    }
    if (EXPSUM) {
        #pragma unroll
        for (int m = 0; m < FM; ++m) {
            #pragma unroll
            for (int r = 0; r < 4; ++r) {
                float v = rs[m][r];
                v += __shfl_xor(v, 1); v += __shfl_xor(v, 2);
                v += __shfl_xor(v, 4); v += __shfl_xor(v, 8);
                if ((lane & 15) == 0) {
                    const int gr = mbase + wr * PM + m * 16 + lr + r;
                    atomicAdd(rowsum + gr, v);
                }
            }
        }
    }
}

// ---------------------------------------------------------------------------
// gemm_bt wrapper: decode (XCD swizzle / ORD / PAIR / QKF / CSKIP), then core.
// PAIR=1 (out-proj, nwg=512, gx=16, gy=8): co-resident (l, l^32) get
//   complementary mt -> per-CU causal work sums to const; same (nt,z).
// ---------------------------------------------------------------------------
template<int BM, int BN, int WM, int WN, int OUT_BF16, int MASK, int CSKIP,
         int CK, int QKF, int EXPSUM, int RSCALE, int ORD, int PAIR>
__launch_bounds__(WM*WN*64)
__global__ void gemm_bt(const u16* __restrict__ Ag, const u16* __restrict__ Bg,
                        const u16* __restrict__ Bg2,
                        void* __restrict__ Cg, void* __restrict__ Cg2,
                        const float* __restrict__ maskp,
                        float* __restrict__ rowsum,
                        int gx, int gy,
                        int K, int lda, int ldb, int ldc,
                        long sA, long sB, long sC, float scale)
{
    constexpr int ASZ = BM * 64, BSZ = BN * 64;
    __shared__ u16 As0[ASZ];
    __shared__ u16 As1[ASZ];
    __shared__ u16 Bs0[BSZ];
    __shared__ u16 Bs1[BSZ];

    // XCD-chunked bijective swizzle (T1): nwg % 8 == 0 for all launches
    const int nwg = gridDim.x;
    const int l   = (blockIdx.x & 7) * (nwg >> 3) + (blockIdx.x >> 3);
    int mt, nt, z, path = 0;
    if (PAIR == 1) {
        const int pairid = l & 7;
        const int f      = (l >> 5) & 1;
        mt = f ? (gx - 1 - pairid) : pairid;
        const int ntz = ((l >> 3) & 3) | (((l >> 6) & 7) << 2);
        nt = ntz & 7;
        z  = ntz >> 3;
    } else if (ORD == 0) {
        mt = l % gx; const int r = l / gx; nt = r % gy; z = r / gy;
    } else {
        nt = l % gy; const int r = l / gy; mt = r % gx; z = r / gx;
    }
    if (QKF) { constexpr int NT = C_DIM / BN; path = nt / NT; nt = nt % NT; }
    if (CSKIP && nt * BN >= (mt + 1) * BM) return;   // above causal diagonal

    const bool kpath = QKF && path;
    const u16* Aa = Ag + (long)z * sA;
    const u16* Bb = (kpath ? Bg2 : Bg) + (long)z * sB;
    void* CoutBase = kpath ? Cg2 : Cg;
    void* Cout = OUT_BF16 ? (void*)((u16*)CoutBase + (long)z * sC)
                          : (void*)((float*)CoutBase + (long)z * sC);
    const float* mp = (MASK && !kpath && maskp) ? maskp + (long)z * sC : nullptr;
    float* rsz = rowsum ? rowsum + (long)z * SEQ : nullptr;

    gemm_core<BM,BN,WM,WN,OUT_BF16,MASK,CK,EXPSUM,RSCALE>(
        As0, As1, Bs0, Bs1, Aa, Bb, Cout, mp, rsz,
        mt, nt, K, lda, ldb, ldc, scale);
}

// ---------------------------------------------------------------------------
// Fused scores + xovT dispatch, LPT-ordered: the LONG xovT blocks (16
// K-tiles) occupy bids [0,512) so they start at t=0; the short scores
// blocks (<=2 K-tiles) fill bids [512,1536) and drain into vacated slots.
// Decodes identical to round-17 (verified), just range-shifted.
// ---------------------------------------------------------------------------
__launch_bounds__(256)
__global__ void scores_xov_fused(const u16* __restrict__ qm,
                                 const u16* __restrict__ kk,
                                 u16* __restrict__ sc,
                                 float* __restrict__ rowsum,
                                 const u16* __restrict__ ovT,
                                 const u16* __restrict__ xb,
                                 u16* __restrict__ xovT)
{
    __shared__ u16 As0[128*64];
    __shared__ u16 As1[128*64];
    __shared__ u16 Bs0[128*64];
    __shared__ u16 Bs1[128*64];

    const int bid = blockIdx.x;
    if (bid < 512) {
        // xovT[e][k] = sum_d ovT[e][d] * xb[k][d]  (M=1024, N=8192, K=1024)
        // ORD=0 decode over local grid (nwg=512, gx=8, gy=64, z=0)
        const int l = (bid & 7) * 64 + (bid >> 3);
        const int mt = l % 8;
        const int nt = l / 8;                        // 0..63
        gemm_core<128,128,2,2, 1,0,0,0,0>(
            As0, As1, Bs0, Bs1,
            ovT, xb, xovT, nullptr, nullptr,
            mt, nt, D_MODEL, D_MODEL, D_MODEL, BS_ROWS, 1.0f);
    } else {
        // scores: Pu = exp(qm @ kk^T / D), causal-zeroed, rowsum atomics
        // PAIR=2 decode (local nwg=1024, gx=gy=16, BATCH=4) — verified
        const int sb = bid - 512;                    // 0..1023 (512%8==0)
        const int l = (sb & 7) * 128 + (sb >> 3);
        const int f = (l >> 5) & 1;
        const int p = (l & 31) | ((l >> 6) << 5);    // 0..511
        const int z = p >> 7;
        const int q = p & 127;
        const int mt = f ? 15 - (q & 15) : (q & 15);
        const int nt = f ? 15 - (q >> 4) : (q >> 4);
        if (nt > mt) return;                         // above causal diagonal
        gemm_core<128,128,2,2, 1,0,0,1,0>(
            As0, As1, Bs0, Bs1,
            qm + (long)z * SEQ * C_DIM,
            kk + (long)z * SEQ * C_DIM,
            sc + (long)z * SEQ * SEQ,
            nullptr,
            rowsum + (long)z * SEQ,
            mt, nt, C_DIM, C_DIM, C_DIM, SEQ, 1.0f / D_MODEL);
    }
}

// ---------------------------------------------------------------------------
// Merged prep: one dispatch, bid-range roles.
//   [0,2048):        x fp32->bf16 (grid-stride) + rowsum zero-fill
//   [2048,2176):     Bmat fp32->bf16 (exact cover)
//   [2176,3200):     ov transpose->ovT  (32x32 tiles, 32x32 grid)
//   [3200,3328):     A transpose->AbT   (4x32 grid)
// ---------------------------------------------------------------------------
__launch_bounds__(256)
__global__ void prep_all(const float* __restrict__ x,  u16* __restrict__ xb,
                         float* __restrict__ rowsum,
                         const float* __restrict__ Bm, u16* __restrict__ Bmb,
                         const float* __restrict__ ov, u16* __restrict__ ovT,
                         const float* __restrict__ A,  u16* __restrict__ AbT)
{
    __shared__ float t[32][33];
    const int bid = blockIdx.x;
    if (bid < 2048) {
        const int gid = bid * 256 + threadIdx.x;
        if (gid < BS_ROWS) rowsum[gid] = 0.f;
        const int n4 = BS_ROWS * D_MODEL / 4;
        for (int i = gid; i < n4; i += 2048 * 256) {
            float4 f = reinterpret_cast<const float4*>(x)[i];
            u16x4 o = { f2bf(f.x), f2bf(f.y), f2bf(f.z), f2bf(f.w) };
            reinterpret_cast<u16x4*>(xb)[i] = o;
        }
    } else if (bid < 2176) {
        const int gid = (bid - 2048) * 256 + threadIdx.x;   // exact cover
        float4 f = reinterpret_cast<const float4*>(Bm)[gid];
        u16x4 o = { f2bf(f.x), f2bf(f.y), f2bf(f.z), f2bf(f.w) };
        reinterpret_cast<u16x4*>(Bmb)[gid] = o;
    } else if (bid < 3200) {
        // ov[D][D] -> ovT[c][r]
        const int local = bid - 2176;
        const int c0 = (local & 31) * 32, r0 = (local >> 5) * 32;
        const int tx = threadIdx.x & 31, ty = threadIdx.x >> 5;
        #pragma unroll
        for (int i = 0; i < 32; i += 8)
            t[ty + i][tx] = ov[(size_t)(r0 + ty + i) * D_MODEL + c0 + tx];
        __syncthreads();
        #pragma unroll
        for (int i = 0; i < 32; i += 8)
            ovT[(size_t)(c0 + ty + i) * D_MODEL + r0 + tx] = f2bf(t[tx][ty + i]);
    } else {
        // A[D][C] -> AbT[c][r]
        const int local = bid - 3200;
        const int c0 = (local & 3) * 32, r0 = (local >> 2) * 32;
        const int tx = threadIdx.x & 31, ty = threadIdx.x >> 5;
        #pragma unroll
        for (int i = 0; i < 32; i += 8)
            t[ty + i][tx] = A[(size_t)(r0 + ty + i) * C_DIM + c0 + tx];
        __syncthreads();
        #pragma unroll
        for (int i = 0; i < 32; i += 8)
            AbT[(size_t)(c0 + ty + i) * D_MODEL + r0 + tx] = f2bf(t[tx][ty + i]);
    }
}

// ---------------------------------------------------------------------------
extern "C" void kernel_launch(void* const* d_in, const int* in_sizes, int n_in,
                              void* d_out, int out_size, void* d_ws, size_t ws_size,
                              hipStream_t stream)
{
    const float* x    = (const float*)d_in[0];
    const float* A    = (const float*)d_in[1];
    const float* Bm   = (const float*)d_in[2];
    const float* ov   = (const float*)d_in[3];
    const float* mask = (const float*)d_in[4];

    // workspace layout: ~70.3 MiB
    char* w = (char*)d_ws;
    u16* xb   = (u16*)w; w += (size_t)BS_ROWS * D_MODEL * 2;   // x bf16 row-major
    u16* AbT  = (u16*)w; w += (size_t)C_DIM * D_MODEL * 2;     // A^T [C][D]
    u16* Bmb  = (u16*)w; w += (size_t)C_DIM * D_MODEL * 2;     // Bmat [C][D]
    u16* ovT  = (u16*)w; w += (size_t)D_MODEL * D_MODEL * 2;   // ov^T [e][d]
    u16* qm   = (u16*)w; w += (size_t)BS_ROWS * C_DIM * 2;     // masked q
    u16* kk   = (u16*)w; w += (size_t)BS_ROWS * C_DIM * 2;     // k
    u16* sc   = (u16*)w; w += (size_t)BATCH * SEQ * SEQ * 2;   // Pu = exp(scores)
    u16* xovT = (u16*)w; w += (size_t)D_MODEL * BS_ROWS * 2;   // (x@ov)^T [e][k]
    float* rowsum = (float*)w; w += (size_t)BS_ROWS * 4;       // softmax denoms

    // merged prep (converts + transposes + rowsum zero): one dispatch
    prep_all<<<3328, 256, 0, stream>>>(x, xb, rowsum, Bm, Bmb, ov, ovT, A, AbT);

    // fused q & k projection: 64x64 tiles, 4 waves; 512 blocks; ORD=1
    gemm_bt<64,64,2,2, 1,1,0,0,1,0,0, 1,0><<<512, 256, 0, stream>>>(
        xb, AbT, Bmb, qm, kk, mask, nullptr,
        /*gx*/128, /*gy*/4,
        D_MODEL, D_MODEL, D_MODEL, C_DIM, 0, 0, 0, 1.0f);

    // fused dispatch, LPT: xovT (512 bids, long) + scores (1024 bids, short)
    scores_xov_fused<<<1536, 256, 0, stream>>>(qm, kk, sc, rowsum, ovT, xb, xovT);

    // out = (Pu @ xovT^T) / rowsum   (per batch, causal K-extent, fp32 out)
    // 128x128, 4 waves; 512 blocks; PAIR=1: complementary-mt pairs
    gemm_bt<128,128,2,2, 0,0,0,1,0,0,1, 0,1><<<512, 256, 0, stream>>>(
        sc, xovT, nullptr, d_out, nullptr, nullptr, rowsum,
        /*gx*/16, /*gy*/8,
        SEQ, SEQ, BS_ROWS, D_MODEL,
        (long)SEQ * SEQ, (long)SEQ /*batch col offset in xovT*/, (long)SEQ * D_MODEL, 1.0f);
}